// Round 9
// baseline (92187.292 us; speedup 1.0000x reference)
//
#include <hip/hip_runtime.h>
#include <hip/hip_bf16.h>

#define TT 512
#define NB 1024

typedef float f32x4 __attribute__((ext_vector_type(4)));
typedef __bf16 bf16x8 __attribute__((ext_vector_type(8)));

// ---- packed weight layout in d_ws (bf16 elems), π-fragment form (verified R3-R8):
//   frag(mt, kt, lane, j) at OFF + ((mt*KT + kt)*512 + lane*8 + j)
//   value = W[kappa][16*mt + (lane&15)]
//   perm matrices: kappa = 32*kt + 16*(j>>2) + 4*(lane>>4) + (j&3)
//   Wcp (consumes x): kappa = 32*kt + 8*(lane>>4) + j
#define OFF_HP 0
#define OFF_CP 65536
#define OFF_M  81920
#define OFF_PO 212992
#define OFF_R1 278528
#define TOT    344064

__global__ __launch_bounds__(256) void pack_weights(
    const float* __restrict__ Whp, const float* __restrict__ Wm,
    const float* __restrict__ Wcp, const float* __restrict__ Whpost,
    const float* __restrict__ Wr1, __bf16* __restrict__ wsp) {
  int id = blockIdx.x * 256 + threadIdx.x;
  if (id >= TOT) return;
  int j = id & 7, lane = (id >> 3) & 63;
  int lq = lane >> 4, l15 = lane & 15;
  int rel, KT; const float* W; bool perm = true;
  if (id < OFF_CP)      { rel = id;          KT = 8;  W = Whp; }
  else if (id < OFF_M)  { rel = id - OFF_CP; KT = 2;  W = Wcp; perm = false; }
  else if (id < OFF_PO) { rel = id - OFF_M;  KT = 16; W = Wm; }
  else if (id < OFF_R1) { rel = id - OFF_PO; KT = 8;  W = Whpost; }
  else                  { rel = id - OFF_R1; KT = 8;  W = Wr1; }
  int ktm = rel >> 9;
  int kt = ktm % KT, mt = ktm / KT;
  int phi = 16 * mt + l15;
  int kk;
  if (perm) {
    int kb = (kt >= 8) ? kt - 8 : kt;          // only mesh has kt>=8
    kk = 32 * kb + 16 * (j >> 2) + 4 * lq + (j & 3);
    if (kt >= 8) kk += 256;                    // cp half of the concat
  } else {
    kk = 32 * kt + 8 * lq + j;
  }
  wsp[id] = (__bf16)W[kk * 256 + phi];
}

__device__ __forceinline__ float tanh_fast(float x) {
  float t = __expf(2.0f * x);
  return 1.0f - __fdividef(2.0f, t + 1.0f);
}

#define MFMA(a, b, c) __builtin_amdgcn_mfma_f32_16x16x32_bf16((a), (b), (c), 0, 0, 0)

// In-register π-pack: B[kt][j] = tanh(acc[2kt + (j>>2)][j&3]) — no LDS.
__device__ __forceinline__ bf16x8 packpair(const f32x4& a0, const f32x4& a1) {
  bf16x8 f;
  #pragma unroll
  for (int r = 0; r < 4; ++r) {
    f[r]     = (__bf16)tanh_fast(a0[r]);
    f[4 + r] = (__bf16)tanh_fast(a1[r]);
  }
  return f;
}

// One wave (64 threads) per WG per CU: the whole RNN cell for 16 batch rows,
// barrier-free. LDS holds Whp (128 KB) + biases; Wcp/Wm/Wpo/Wr1 stream from L2
// through deep rolling windows in one uninterrupted VMEM stream.
__global__ __launch_bounds__(64)
__attribute__((amdgpu_waves_per_eu(1, 1)))
void rnn_seq(
    const float* __restrict__ x, const __bf16* __restrict__ wsp,
    const float* __restrict__ bhp, const float* __restrict__ bcp,
    const float* __restrict__ bm, const float* __restrict__ bhpost,
    const float* __restrict__ br1, const float* __restrict__ Wr2,
    const float* __restrict__ br2, float* __restrict__ out) {
  __shared__ __align__(16) __bf16 whp_l[65536];  // Whp fragments, 128 KB
  __shared__ float lb[6 * 256];                  // bhp,bcp,bm,bhpost,br1,Wr2

  const int lane = threadIdx.x;   // 0..63, one wave
  const int lq = lane >> 4;
  const int l15 = lane & 15;
  const int n0 = blockIdx.x * 16;

  for (int i = lane; i < 8192; i += 64)
    ((bf16x8*)whp_l)[i] = ((const bf16x8*)(wsp + OFF_HP))[i];
  for (int i = lane; i < 256; i += 64) {
    lb[0 * 256 + i] = bhp[i];
    lb[1 * 256 + i] = bcp[i];
    lb[2 * 256 + i] = bm[i];
    lb[3 * 256 + i] = bhpost[i];
    lb[4 * 256 + i] = br1[i];
    lb[5 * 256 + i] = Wr2[i];
  }
  const float br2v = br2[0];
  __syncthreads();   // one-time, single wave

  #define BIAS(a, m) (*(const f32x4*)(lb + (a) * 256 + (m) * 16 + 4 * lq))

  const __bf16* cp_p = wsp + OFF_CP + lane * 8;
  const __bf16* wm_p = wsp + OFF_M  + lane * 8;
  const __bf16* po_p = wsp + OFF_PO + lane * 8;
  const __bf16* r1_p = wsp + OFF_R1 + lane * 8;

  // h state as B-fragments, register-resident forever
  bf16x8 hb[8];
  #pragma unroll
  for (int k = 0; k < 8; ++k)
    #pragma unroll
    for (int j = 0; j < 8; ++j) hb[k][j] = (__bf16)0.0f;

  const float* xbase = x + (size_t)(n0 + l15) * 64 + 8 * lq;
  bf16x8 Bx0, Bx1;
  {
    f32x4 xa = *(const f32x4*)(xbase);
    f32x4 xb = *(const f32x4*)(xbase + 4);
    f32x4 xc = *(const f32x4*)(xbase + 32);
    f32x4 xd = *(const f32x4*)(xbase + 36);
    #pragma unroll
    for (int j = 0; j < 4; ++j) {
      Bx0[j] = (__bf16)xa[j]; Bx0[4 + j] = (__bf16)xb[j];
      Bx1[j] = (__bf16)xc[j]; Bx1[4 + j] = (__bf16)xd[j];
    }
  }

  for (int t = 0; t < TT; ++t) {
    // ---- issue r1 (24-deep) + cp (8-deep) streams, then hp from LDS ----
    bf16x8 w1[24];
    #pragma unroll
    for (int p = 0; p < 24; ++p) w1[p] = *(const bf16x8*)(r1_p + p * 512);
    bf16x8 cw[8];
    #pragma unroll
    for (int p = 0; p < 8; ++p) cw[p] = *(const bf16x8*)(cp_p + p * 512);

    // hp = h @ Whp + bhp  (A from LDS, B = hb in regs; 128 MFMAs)
    f32x4 acc[16];
    #pragma unroll
    for (int mt = 0; mt < 16; ++mt) acc[mt] = BIAS(0, mt);
    #pragma unroll
    for (int kt = 0; kt < 8; ++kt)
      #pragma unroll
      for (int mt = 0; mt < 16; ++mt) {
        bf16x8 a = *(const bf16x8*)(whp_l + (size_t)(mt * 8 + kt) * 512 + lane * 8);
        acc[mt] = MFMA(a, hb[kt], acc[mt]);
      }
    bf16x8 mHB[8];
    #pragma unroll
    for (int k = 0; k < 8; ++k) mHB[k] = packpair(acc[2 * k], acc[2 * k + 1]);

    // cp = x @ Wcp + bcp  (32 frags, rolling window 8)
    f32x4 cacc[16];
    #pragma unroll
    for (int mt = 0; mt < 16; ++mt) cacc[mt] = BIAS(1, mt);
    #pragma unroll
    for (int i = 0; i < 32; ++i) {          // i = mt*2 + kt
      cacc[i >> 1] = MFMA(cw[i & 7], (i & 1) ? Bx1 : Bx0, cacc[i >> 1]);
      if (i + 8 < 32) cw[i & 7] = *(const bf16x8*)(cp_p + (i + 8) * 512);
    }
    bf16x8 mCB[8];
    #pragma unroll
    for (int k = 0; k < 8; ++k) mCB[k] = packpair(cacc[2 * k], cacc[2 * k + 1]);

    // r1 = h @ Wr1 + br1 -> relu -> dot w2  (128 frags, window 24, 2 halves)
    float pr = 0.f;
    #pragma unroll
    for (int half = 0; half < 2; ++half) {
      f32x4 racc[8];
      #pragma unroll
      for (int m8 = 0; m8 < 8; ++m8) racc[m8] = BIAS(4, half * 8 + m8);
      #pragma unroll
      for (int i = 0; i < 64; ++i) {        // frag = half*64 + i = m8*8 + kt
        int frag = half * 64 + i;
        racc[i >> 3] = MFMA(w1[frag % 24], hb[i & 7], racc[i >> 3]);
        if (frag + 24 < 128)
          w1[frag % 24] = *(const bf16x8*)(r1_p + (frag + 24) * 512);
      }
      #pragma unroll
      for (int m8 = 0; m8 < 8; ++m8) {
        const f32x4 wv2 = *(const f32x4*)(lb + 5 * 256 + (half * 8 + m8) * 16 + 4 * lq);
        #pragma unroll
        for (int r = 0; r < 4; ++r) pr += fmaxf(racc[m8][r], 0.f) * wv2[r];
      }
    }
    pr += __shfl_xor(pr, 16, 64);
    pr += __shfl_xor(pr, 32, 64);
    if (t > 0 && lane < 16)
      out[(size_t)(t - 1) * NB + n0 + lane] = pr + br2v;

    // ---- mesh: u = [hp|cp] @ Wm + bm  (256 frags, window 24) ----
    bf16x8 wm[24];
    #pragma unroll
    for (int p = 0; p < 24; ++p) wm[p] = *(const bf16x8*)(wm_p + p * 512);
    f32x4 uacc[16];
    #pragma unroll
    for (int mt = 0; mt < 16; ++mt) uacc[mt] = BIAS(2, mt);
    #pragma unroll
    for (int i = 0; i < 256; ++i) {         // i = mt*16 + kt
      int kt = i & 15;
      bf16x8 B = (kt < 8) ? mHB[kt] : mCB[kt - 8];
      uacc[i >> 4] = MFMA(wm[i % 24], B, uacc[i >> 4]);
      if (i + 24 < 256) wm[i % 24] = *(const bf16x8*)(wm_p + (i + 24) * 512);
    }
    bf16x8 uB[8];
    #pragma unroll
    for (int k = 0; k < 8; ++k) uB[k] = packpair(uacc[2 * k], uacc[2 * k + 1]);

    // ---- po: h = tanh(u @ Whpost + bhpost)  (128 frags, window 24) ----
    bf16x8 pw[24];
    #pragma unroll
    for (int p = 0; p < 24; ++p) pw[p] = *(const bf16x8*)(po_p + p * 512);
    // x prefetch for t+1 rides the same stream
    int tn = (t + 1 < TT) ? t + 1 : TT - 1;
    const float* xp = xbase + (size_t)tn * NB * 64;
    f32x4 xa = *(const f32x4*)(xp);
    f32x4 xb = *(const f32x4*)(xp + 4);
    f32x4 xc = *(const f32x4*)(xp + 32);
    f32x4 xd = *(const f32x4*)(xp + 36);
    f32x4 pacc[16];
    #pragma unroll
    for (int mt = 0; mt < 16; ++mt) pacc[mt] = BIAS(3, mt);
    #pragma unroll
    for (int i = 0; i < 128; ++i) {         // i = mt*8 + kt
      pacc[i >> 3] = MFMA(pw[i % 24], uB[i & 7], pacc[i >> 3]);
      if (i + 24 < 128) pw[i % 24] = *(const bf16x8*)(po_p + (i + 24) * 512);
    }
    #pragma unroll
    for (int k = 0; k < 8; ++k) hb[k] = packpair(pacc[2 * k], pacc[2 * k + 1]);
    #pragma unroll
    for (int j = 0; j < 4; ++j) {
      Bx0[j] = (__bf16)xa[j]; Bx0[4 + j] = (__bf16)xb[j];
      Bx1[j] = (__bf16)xc[j]; Bx1[4 + j] = (__bf16)xd[j];
    }
  }

  // ---- tail: regressor on final h -> out[TT-1] ----
  {
    float pr = 0.f;
    bf16x8 w1[16];
    #pragma unroll
    for (int p = 0; p < 16; ++p) w1[p] = *(const bf16x8*)(r1_p + p * 512);
    #pragma unroll
    for (int half = 0; half < 2; ++half) {
      f32x4 racc[8];
      #pragma unroll
      for (int m8 = 0; m8 < 8; ++m8) racc[m8] = BIAS(4, half * 8 + m8);
      #pragma unroll
      for (int i = 0; i < 64; ++i) {
        int frag = half * 64 + i;
        racc[i >> 3] = MFMA(w1[frag & 15], hb[i & 7], racc[i >> 3]);
        if (frag + 16 < 128)
          w1[frag & 15] = *(const bf16x8*)(r1_p + (frag + 16) * 512);
      }
      #pragma unroll
      for (int m8 = 0; m8 < 8; ++m8) {
        const f32x4 wv2 = *(const f32x4*)(lb + 5 * 256 + (half * 8 + m8) * 16 + 4 * lq);
        #pragma unroll
        for (int r = 0; r < 4; ++r) pr += fmaxf(racc[m8][r], 0.f) * wv2[r];
      }
    }
    pr += __shfl_xor(pr, 16, 64);
    pr += __shfl_xor(pr, 32, 64);
    if (lane < 16)
      out[(size_t)(TT - 1) * NB + n0 + lane] = pr + br2v;
  }
}

extern "C" void kernel_launch(void* const* d_in, const int* in_sizes, int n_in,
                              void* d_out, int out_size, void* d_ws, size_t ws_size,
                              hipStream_t stream) {
  const float* x      = (const float*)d_in[0];
  const float* Whp    = (const float*)d_in[1];
  const float* bhp    = (const float*)d_in[2];
  const float* Wcp    = (const float*)d_in[3];
  const float* bcp    = (const float*)d_in[4];
  const float* Wm     = (const float*)d_in[5];
  const float* bm     = (const float*)d_in[6];
  const float* Whpost = (const float*)d_in[7];
  const float* bhpost = (const float*)d_in[8];
  const float* Wr1    = (const float*)d_in[9];
  const float* br1    = (const float*)d_in[10];
  const float* Wr2    = (const float*)d_in[11];
  const float* br2    = (const float*)d_in[12];
  __bf16* wsp = (__bf16*)d_ws;
  float*  out = (float*)d_out;

  if (ws_size < (size_t)TOT * sizeof(__bf16)) return;

  pack_weights<<<(TOT + 255) / 256, 256, 0, stream>>>(Whp, Wm, Wcp, Whpost, Wr1, wsp);
  rnn_seq<<<64, 64, 0, stream>>>(x, wsp, bhp, bcp, bm, bhpost, br1, Wr2, br2, out);
}

// Round 10
// 6327.291 us; speedup vs baseline: 14.5698x; 14.5698x over previous
//
#include <hip/hip_runtime.h>
#include <hip/hip_bf16.h>

#define TT 512
#define NB 1024

typedef float f32x4 __attribute__((ext_vector_type(4)));
typedef __bf16 bf16x8 __attribute__((ext_vector_type(8)));

// ---- packed weight layout in d_ws (bf16 elems), π-fragment form (verified R3-R9):
//   frag(mt, kt, lane, j) at OFF + ((mt*KT + kt)*512 + lane*8 + j)
//   value = W[kappa][16*mt + (lane&15)]
//   perm matrices: kappa = 32*kt + 16*(j>>2) + 4*(lane>>4) + (j&3)
//   Wcp (consumes x): kappa = 32*kt + 8*(lane>>4) + j
#define OFF_HP 0
#define OFF_CP 65536
#define OFF_M  81920
#define OFF_PO 212992
#define OFF_R1 278528
#define TOT    344064

__global__ __launch_bounds__(256) void pack_weights(
    const float* __restrict__ Whp, const float* __restrict__ Wm,
    const float* __restrict__ Wcp, const float* __restrict__ Whpost,
    const float* __restrict__ Wr1, __bf16* __restrict__ wsp) {
  int id = blockIdx.x * 256 + threadIdx.x;
  if (id >= TOT) return;
  int j = id & 7, lane = (id >> 3) & 63;
  int lq = lane >> 4, l15 = lane & 15;
  int rel, KT; const float* W; bool perm = true;
  if (id < OFF_CP)      { rel = id;          KT = 8;  W = Whp; }
  else if (id < OFF_M)  { rel = id - OFF_CP; KT = 2;  W = Wcp; perm = false; }
  else if (id < OFF_PO) { rel = id - OFF_M;  KT = 16; W = Wm; }
  else if (id < OFF_R1) { rel = id - OFF_PO; KT = 8;  W = Whpost; }
  else                  { rel = id - OFF_R1; KT = 8;  W = Wr1; }
  int ktm = rel >> 9;
  int kt = ktm % KT, mt = ktm / KT;
  int phi = 16 * mt + l15;
  int kk;
  if (perm) {
    int kb = (kt >= 8) ? kt - 8 : kt;          // only mesh has kt>=8
    kk = 32 * kb + 16 * (j >> 2) + 4 * lq + (j & 3);
    if (kt >= 8) kk += 256;                    // cp half of the concat
  } else {
    kk = 32 * kt + 8 * lq + j;
  }
  wsp[id] = (__bf16)W[kk * 256 + phi];
}

__device__ __forceinline__ float tanh_fast(float x) {
  float t = __expf(2.0f * x);
  return 1.0f - __fdividef(2.0f, t + 1.0f);
}

#define MFMA(a, b, c) __builtin_amdgcn_mfma_f32_16x16x32_bf16((a), (b), (c), 0, 0, 0)

// Workgroup barrier that does NOT drain the VMEM queue: wait only for this
// wave's outstanding LDS ops (lgkmcnt=0; vmcnt=63, expcnt=7 untouched), then
// s_barrier. Weight prefetches issued before this stay in flight across it —
// the thing __syncthreads() (s_waitcnt vmcnt(0)) forbids.
__device__ __forceinline__ void soft_barrier() {
  __builtin_amdgcn_s_waitcnt(0xC07F);
  __builtin_amdgcn_s_barrier();
}

// tanh + pack this wave's two accumulators into ONE full B-fragment (kt = wv):
// B[wv][j] = tanh(acc[j>>2][j&3]); conflict-free ds_write_b128 at lane*16.
__device__ __forceinline__ void pack2(__bf16* region, int wv, int lane,
                                      const f32x4& a0, const f32x4& a1) {
  bf16x8 f;
  #pragma unroll
  for (int r = 0; r < 4; ++r) {
    f[r]     = (__bf16)tanh_fast(a0[r]);
    f[4 + r] = (__bf16)tanh_fast(a1[r]);
  }
  *(bf16x8*)(region + wv * 512 + lane * 8) = f;
}

__global__ __launch_bounds__(512, 2) void rnn_seq(
    const float* __restrict__ x, const __bf16* __restrict__ wsp,
    const float* __restrict__ bhp, const float* __restrict__ bcp,
    const float* __restrict__ bm, const float* __restrict__ bhpost,
    const float* __restrict__ br1, const float* __restrict__ Wr2,
    const float* __restrict__ br2, float* __restrict__ out) {
  __shared__ __align__(16) __bf16 hB[8 * 512];   // h state as B-frags
  __shared__ __align__(16) __bf16 mB[16 * 512];  // [hpB | cpB] for mesh
  __shared__ __align__(16) __bf16 uB[8 * 512];   // mesh output
  __shared__ float lb[6 * 256];                  // bhp,bcp,bm,bhpost,br1,Wr2
  __shared__ float outp[128];

  const int tid  = threadIdx.x;
  const int wv   = tid >> 6;      // 0..7, owns m-tiles 2wv, 2wv+1
  const int lane = tid & 63;
  const int lq   = lane >> 4, l15 = lane & 15;
  const int n0   = blockIdx.x * 16;
  const int mt0  = 2 * wv;

  if (tid < 256) {
    lb[0 * 256 + tid] = bhp[tid];
    lb[1 * 256 + tid] = bcp[tid];
    lb[2 * 256 + tid] = bm[tid];
    lb[3 * 256 + tid] = bhpost[tid];
    lb[4 * 256 + tid] = br1[tid];
    lb[5 * 256 + tid] = Wr2[tid];
  }
  for (int i = tid; i < 8 * 512; i += 512) hB[i] = (__bf16)0.0f;  // h0 = 0
  const float br2v = br2[0];

  // bias accessor: element r of f32x4 <-> feature 16*mt + 4*lq + r
  #define BIAS(a, m) (*(const f32x4*)(lb + (a) * 256 + (m) * 16 + 4 * lq))
  const f32x4 w2a = *(const f32x4*)(Wr2 + mt0 * 16 + 4 * lq);
  const f32x4 w2b = *(const f32x4*)(Wr2 + (mt0 + 1) * 16 + 4 * lq);

  // A-frag bases for this wave's mt pair: frag(mt0,kt) at +kt*512,
  // frag(mt0+1,kt) at +(KT+kt)*512
  const __bf16* hp_p = wsp + OFF_HP + (size_t)(mt0 * 8) * 512 + lane * 8;
  const __bf16* r1_p = wsp + OFF_R1 + (size_t)(mt0 * 8) * 512 + lane * 8;
  const __bf16* cp_p = wsp + OFF_CP + (size_t)(mt0 * 2) * 512 + lane * 8;
  const __bf16* po_p = wsp + OFF_PO + (size_t)(mt0 * 8) * 512 + lane * 8;
  const __bf16* wm_p = wsp + OFF_M  + (size_t)(mt0 * 16) * 512 + lane * 8;

  const float* xbase = x + (size_t)(n0 + l15) * 64 + 8 * lq;
  f32x4 xr0 = *(const f32x4*)(xbase);
  f32x4 xr1 = *(const f32x4*)(xbase + 4);
  f32x4 xr2 = *(const f32x4*)(xbase + 32);
  f32x4 xr3 = *(const f32x4*)(xbase + 36);

  __syncthreads();   // one-time init barrier (hard is fine here)

  // S1 windows live ACROSS the loop: issued pre-B3 each step (in flight over
  // the barrier), consumed in the next step's stage 1.
  bf16x8 w[8];       // {hp(mt0), hp(mt1), r1(mt0), r1(mt1)} x 2-kt lookahead
  bf16x8 cpw[4];
  #pragma unroll
  for (int p = 0; p < 2; ++p) {
    w[4 * p + 0] = *(const bf16x8*)(hp_p + p * 512);
    w[4 * p + 1] = *(const bf16x8*)(hp_p + (8 + p) * 512);
    w[4 * p + 2] = *(const bf16x8*)(r1_p + p * 512);
    w[4 * p + 3] = *(const bf16x8*)(r1_p + (8 + p) * 512);
  }
  #pragma unroll
  for (int p = 0; p < 4; ++p) cpw[p] = *(const bf16x8*)(cp_p + p * 512);

  for (int t = 0; t < TT; ++t) {
    // ---- stage 1: hp = h@Whp+bhp (dual with r1 = h@Wr1+br1) ; cp = x@Wcp+bcp ----
    bf16x8 Bx0, Bx1;
    #pragma unroll
    for (int j = 0; j < 4; ++j) {
      Bx0[j] = (__bf16)xr0[j]; Bx0[4 + j] = (__bf16)xr1[j];
      Bx1[j] = (__bf16)xr2[j]; Bx1[4 + j] = (__bf16)xr3[j];
    }
    f32x4 ah0 = BIAS(0, mt0), ah1 = BIAS(0, mt0 + 1);
    f32x4 ar0 = BIAS(4, mt0), ar1 = BIAS(4, mt0 + 1);
    #pragma unroll
    for (int kt = 0; kt < 8; ++kt) {
      bf16x8 B = *(const bf16x8*)(hB + kt * 512 + lane * 8);
      int s = (kt & 1) * 4;
      ah0 = MFMA(w[s + 0], B, ah0);
      ah1 = MFMA(w[s + 1], B, ah1);
      ar0 = MFMA(w[s + 2], B, ar0);
      ar1 = MFMA(w[s + 3], B, ar1);
      if (kt + 2 < 8) {
        w[s + 0] = *(const bf16x8*)(hp_p + (kt + 2) * 512);
        w[s + 1] = *(const bf16x8*)(hp_p + (8 + kt + 2) * 512);
        w[s + 2] = *(const bf16x8*)(r1_p + (kt + 2) * 512);
        w[s + 3] = *(const bf16x8*)(r1_p + (8 + kt + 2) * 512);
      }
    }
    f32x4 ac0 = BIAS(1, mt0), ac1 = BIAS(1, mt0 + 1);
    ac0 = MFMA(cpw[0], Bx0, ac0); ac0 = MFMA(cpw[1], Bx1, ac0);
    ac1 = MFMA(cpw[2], Bx0, ac1); ac1 = MFMA(cpw[3], Bx1, ac1);

    pack2(mB,           wv, lane, ah0, ah1);
    pack2(mB + 8 * 512, wv, lane, ac0, ac1);
    {
      float p = 0.f;
      #pragma unroll
      for (int r = 0; r < 4; ++r)
        p += fmaxf(ar0[r], 0.f) * w2a[r] + fmaxf(ar1[r], 0.f) * w2b[r];
      p += __shfl_xor(p, 16, 64);
      p += __shfl_xor(p, 32, 64);
      if (lane < 16) outp[wv * 16 + lane] = p;
    }
    // stage-2 weight window issued BEFORE the barrier — stays in flight
    bf16x8 m[12];
    #pragma unroll
    for (int p = 0; p < 6; ++p) {
      m[2 * p + 0] = *(const bf16x8*)(wm_p + p * 512);
      m[2 * p + 1] = *(const bf16x8*)(wm_p + (16 + p) * 512);
    }
    soft_barrier();  // B1 (lgkm only)

    // ---- stage 2: u = cat @ Wm + bm ; store out[t-1] ; prefetch next x ----
    if (t > 0 && tid < 16) {
      float s = br2v;
      #pragma unroll
      for (int w8 = 0; w8 < 8; ++w8) s += outp[w8 * 16 + tid];
      out[(size_t)(t - 1) * NB + n0 + tid] = s;
    }
    {
      int tn = (t + 1 < TT) ? t + 1 : TT - 1;
      const float* xp = xbase + (size_t)tn * NB * 64;
      xr0 = *(const f32x4*)(xp);      xr1 = *(const f32x4*)(xp + 4);
      xr2 = *(const f32x4*)(xp + 32); xr3 = *(const f32x4*)(xp + 36);
    }
    f32x4 am0 = BIAS(2, mt0), am1 = BIAS(2, mt0 + 1);
    #pragma unroll
    for (int kt = 0; kt < 16; ++kt) {
      bf16x8 B = *(const bf16x8*)(mB + kt * 512 + lane * 8);
      int s = (kt % 6) * 2;
      am0 = MFMA(m[s + 0], B, am0);
      am1 = MFMA(m[s + 1], B, am1);
      if (kt + 6 < 16) {
        m[s + 0] = *(const bf16x8*)(wm_p + (kt + 6) * 512);
        m[s + 1] = *(const bf16x8*)(wm_p + (16 + kt + 6) * 512);
      }
    }
    pack2(uB, wv, lane, am0, am1);
    // stage-3 weight window issued BEFORE the barrier
    bf16x8 pw[8];
    #pragma unroll
    for (int p = 0; p < 4; ++p) {
      pw[2 * p + 0] = *(const bf16x8*)(po_p + p * 512);
      pw[2 * p + 1] = *(const bf16x8*)(po_p + (8 + p) * 512);
    }
    soft_barrier();  // B2

    // ---- stage 3: h = tanh(u @ Whpost + bhpost) ----
    f32x4 ap0 = BIAS(3, mt0), ap1 = BIAS(3, mt0 + 1);
    #pragma unroll
    for (int kt = 0; kt < 8; ++kt) {
      bf16x8 B = *(const bf16x8*)(uB + kt * 512 + lane * 8);
      int s = (kt & 3) * 2;
      ap0 = MFMA(pw[s + 0], B, ap0);
      ap1 = MFMA(pw[s + 1], B, ap1);
      if (kt + 4 < 8) {
        pw[s + 0] = *(const bf16x8*)(po_p + (kt + 4) * 512);
        pw[s + 1] = *(const bf16x8*)(po_p + (8 + kt + 4) * 512);
      }
    }
    pack2(hB, wv, lane, ap0, ap1);
    // next step's stage-1 windows issued BEFORE the barrier
    #pragma unroll
    for (int p = 0; p < 2; ++p) {
      w[4 * p + 0] = *(const bf16x8*)(hp_p + p * 512);
      w[4 * p + 1] = *(const bf16x8*)(hp_p + (8 + p) * 512);
      w[4 * p + 2] = *(const bf16x8*)(r1_p + p * 512);
      w[4 * p + 3] = *(const bf16x8*)(r1_p + (8 + p) * 512);
    }
    #pragma unroll
    for (int p = 0; p < 4; ++p) cpw[p] = *(const bf16x8*)(cp_p + p * 512);
    soft_barrier();  // B3
  }

  // ---- tail: regressor on final h ----
  {
    bf16x8 tw[8];
    #pragma unroll
    for (int p = 0; p < 4; ++p) {
      tw[2 * p + 0] = *(const bf16x8*)(r1_p + p * 512);
      tw[2 * p + 1] = *(const bf16x8*)(r1_p + (8 + p) * 512);
    }
    f32x4 ar0 = BIAS(4, mt0), ar1 = BIAS(4, mt0 + 1);
    #pragma unroll
    for (int kt = 0; kt < 8; ++kt) {
      bf16x8 B = *(const bf16x8*)(hB + kt * 512 + lane * 8);
      int s = (kt & 3) * 2;
      ar0 = MFMA(tw[s + 0], B, ar0);
      ar1 = MFMA(tw[s + 1], B, ar1);
      if (kt + 4 < 8) {
        tw[s + 0] = *(const bf16x8*)(r1_p + (kt + 4) * 512);
        tw[s + 1] = *(const bf16x8*)(r1_p + (8 + kt + 4) * 512);
      }
    }
    float p = 0.f;
    #pragma unroll
    for (int r = 0; r < 4; ++r)
      p += fmaxf(ar0[r], 0.f) * w2a[r] + fmaxf(ar1[r], 0.f) * w2b[r];
    p += __shfl_xor(p, 16, 64);
    p += __shfl_xor(p, 32, 64);
    if (lane < 16) outp[wv * 16 + lane] = p;
    __syncthreads();
    if (tid < 16) {
      float s = br2v;
      #pragma unroll
      for (int w8 = 0; w8 < 8; ++w8) s += outp[w8 * 16 + tid];
      out[(size_t)(TT - 1) * NB + n0 + tid] = s;
    }
  }
}

extern "C" void kernel_launch(void* const* d_in, const int* in_sizes, int n_in,
                              void* d_out, int out_size, void* d_ws, size_t ws_size,
                              hipStream_t stream) {
  const float* x      = (const float*)d_in[0];
  const float* Whp    = (const float*)d_in[1];
  const float* bhp    = (const float*)d_in[2];
  const float* Wcp    = (const float*)d_in[3];
  const float* bcp    = (const float*)d_in[4];
  const float* Wm     = (const float*)d_in[5];
  const float* bm     = (const float*)d_in[6];
  const float* Whpost = (const float*)d_in[7];
  const float* bhpost = (const float*)d_in[8];
  const float* Wr1    = (const float*)d_in[9];
  const float* br1    = (const float*)d_in[10];
  const float* Wr2    = (const float*)d_in[11];
  const float* br2    = (const float*)d_in[12];
  __bf16* wsp = (__bf16*)d_ws;
  float*  out = (float*)d_out;

  if (ws_size < (size_t)TOT * sizeof(__bf16)) return;

  pack_weights<<<(TOT + 255) / 256, 256, 0, stream>>>(Whp, Wm, Wcp, Whpost, Wr1, wsp);
  rnn_seq<<<64, 512, 0, stream>>>(x, wsp, bhp, bcp, bm, bhpost, br1, Wr2, br2, out);
}